// Round 1
// baseline (303.227 us; speedup 1.0000x reference)
//
#include <hip/hip_runtime.h>
#include <hip/hip_bf16.h>

// ResidualSSM, 3-kernel prefix decomposition. B=8, L=4096, D=1024.
// KA: fused full-row pass — diff outputs (4-tap, rolling float4 history) for
//     diff half + per-32-row MA partial sums, one coalesced read of u (float4/lane).
// K2: in-place scan of 128 subtile sums per (b,ch) + (w,k0,km) table (64 rows).
// K3: MA outputs, float4 per thread (4 channels); initial window sum from scanned
//     prefixes (min-side fix-up <=16 loads), then acc += x[t]-x[t-w] with 4-deep
//     double-buffered float4 prefetch. No LDS.
// Dtype self-detected per-kernel from diff_kernel[0] bit pattern (fp32 vs bf16).

namespace {
constexpr int B_ = 8, L_ = 4096, D_ = 1024, NRUN = 16;
constexpr int SUB = 32, NSUB = L_ / SUB;                 // 128
constexpr size_t NPART = (size_t)B_ * NRUN * NSUB * 32;  // 524288 floats
constexpr int KA_BLOCKS = B_ * NSUB;                     // 1024, 256 thr
constexpr int K3_BLOCKS = (B_ * 128 * NSUB) / 256;       // 512, 256 thr

template<bool BF> __device__ __forceinline__ float ldx(const void* p, size_t i) {
    if constexpr (BF) return __bfloat162float(((const __hip_bfloat16*)p)[i]);
    else              return ((const float*)p)[i];
}
__device__ __forceinline__ unsigned short f2bf_bits(float f) {
    __hip_bfloat16 h = __float2bfloat16(f);
    unsigned short u; __builtin_memcpy(&u, &h, 2); return u;
}
template<bool BF> __device__ __forceinline__ float4 ld4(const void* p, size_t i) {
    if constexpr (BF) {
        const ushort4 r = *reinterpret_cast<const ushort4*>(
            reinterpret_cast<const unsigned short*>(p) + i);
        return make_float4(__builtin_bit_cast(float, (unsigned)r.x << 16),
                           __builtin_bit_cast(float, (unsigned)r.y << 16),
                           __builtin_bit_cast(float, (unsigned)r.z << 16),
                           __builtin_bit_cast(float, (unsigned)r.w << 16));
    } else {
        return *reinterpret_cast<const float4*>(reinterpret_cast<const float*>(p) + i);
    }
}
template<bool BF> __device__ __forceinline__ void st4(void* p, size_t i, float4 v) {
    if constexpr (BF) {
        const ushort4 r = make_ushort4(f2bf_bits(v.x), f2bf_bits(v.y),
                                       f2bf_bits(v.z), f2bf_bits(v.w));
        *reinterpret_cast<ushort4*>(reinterpret_cast<unsigned short*>(p) + i) = r;
    } else {
        *reinterpret_cast<float4*>(reinterpret_cast<float*>(p) + i) = v;
    }
}
__device__ __forceinline__ bool isbf(const void* dk) {
    return *(const unsigned*)dk == 0x00003F80u;   // bf16 {1.0, 0.0} vs fp32 1.0f
}

// ---------------- KA (fused K1) ----------------
// grid 1024 = b(8) x sub(128); block 256.
// tid 0..127  : diff half. run=tid>>3, qq=tid&7, ch=run*64+qq*4, row=run*4+(qq>>1)
// tid 128..255: MA half.   run=i>>3,  qq=i&7,  ch=run*64+32+qq*4, cm=qq*4
// Wave-uniform branch (waves 0-1 diff, 2-3 MA); loads are 8x128B segments/wave.
template<bool BF>
__device__ void ka_body(const void* __restrict__ u, const void* __restrict__ dk,
                        void* __restrict__ out, float* __restrict__ partials) {
    const int blk = blockIdx.x;
    const int b = blk >> 7, sub = blk & 127;
    const int t0 = sub * SUB;
    const int tid = threadIdx.x;
    if (tid < 128) {                                   // ---- diff half ----
        const int run = tid >> 3, qq = tid & 7;
        const int ch  = run * 64 + qq * 4;
        const int row = run * 4 + (qq >> 1);
        const float c0 = ldx<BF>(dk, (size_t)row * 4 + 0);
        const float c1 = ldx<BF>(dk, (size_t)row * 4 + 1);
        const float c2 = ldx<BF>(dk, (size_t)row * 4 + 2);
        const float c3 = ldx<BF>(dk, (size_t)row * 4 + 3);
        const size_t base = (size_t)b * L_ * D_ + ch;
        const float4 z4 = make_float4(0.f, 0.f, 0.f, 0.f);
        float4 p1 = (t0 >= 1) ? ld4<BF>(u, base + (size_t)(t0 - 1) * D_) : z4;
        float4 p2 = (t0 >= 2) ? ld4<BF>(u, base + (size_t)(t0 - 2) * D_) : z4;
        float4 p3 = (t0 >= 3) ? ld4<BF>(u, base + (size_t)(t0 - 3) * D_) : z4;
        #pragma unroll
        for (int bb = 0; bb < SUB; bb += 8) {
            float4 v[8];
            #pragma unroll
            for (int k = 0; k < 8; ++k)
                v[k] = ld4<BF>(u, base + (size_t)(t0 + bb + k) * D_);
            #pragma unroll
            for (int k = 0; k < 8; ++k) {
                float4 y;
                y.x = c0 * v[k].x + c1 * p1.x + c2 * p2.x + c3 * p3.x;
                y.y = c0 * v[k].y + c1 * p1.y + c2 * p2.y + c3 * p3.y;
                y.z = c0 * v[k].z + c1 * p1.z + c2 * p2.z + c3 * p3.z;
                y.w = c0 * v[k].w + c1 * p1.w + c2 * p2.w + c3 * p3.w;
                st4<BF>(out, base + (size_t)(t0 + bb + k) * D_, y);
                p3 = p2; p2 = p1; p1 = v[k];
            }
        }
    } else {                                           // ---- MA partials ----
        const int i = tid - 128;
        const int run = i >> 3, qq = i & 7;
        const int ch = run * 64 + 32 + qq * 4;
        const int cm = qq * 4;
        const size_t base = (size_t)b * L_ * D_ + ch;
        float4 acc = make_float4(0.f, 0.f, 0.f, 0.f);
        #pragma unroll
        for (int bb = 0; bb < SUB; bb += 8) {
            float4 v[8];
            #pragma unroll
            for (int k = 0; k < 8; ++k)
                v[k] = ld4<BF>(u, base + (size_t)(t0 + bb + k) * D_);
            #pragma unroll
            for (int k = 0; k < 8; ++k) {
                acc.x += v[k].x; acc.y += v[k].y; acc.z += v[k].z; acc.w += v[k].w;
            }
        }
        *reinterpret_cast<float4*>(
            partials + ((size_t)(b * NRUN + run) * NSUB + sub) * 32 + cm) = acc;
    }
}
__global__ __launch_bounds__(256)
void ka_kernel(const void* __restrict__ u, const void* __restrict__ dk,
               void* __restrict__ out, float* __restrict__ partials) {
    if (isbf(dk)) ka_body<true >(u, dk, out, partials);
    else          ka_body<false>(u, dk, out, partials);
}

// ---------------- K2 ----------------
template<bool BF>
__device__ void k2_body(const void* __restrict__ mk, float* __restrict__ partials,
                        float* __restrict__ wtab) {
    if (blockIdx.x == 0) {                       // (w,k0,km) table, 64 MA rows
        const int r = threadIdx.x;
        int lo = 1, hi = 719;
        while (hi - lo > 1) { const int mid = (lo + hi) >> 1;
            if (ldx<BF>(mk, (size_t)r * 720 + mid) != 0.f) lo = mid; else hi = mid; }
        wtab[r * 4 + 0] = (float)hi;
        wtab[r * 4 + 1] = ldx<BF>(mk, (size_t)r * 720 + 0);
        wtab[r * 4 + 2] = ldx<BF>(mk, (size_t)r * 720 + 1);
    }
    const int seq = blockIdx.x * 64 + threadIdx.x;
    const int ch = seq & 31, run = (seq >> 5) & 15, b = seq >> 9;
    float* p = partials + (size_t)(b * NRUN + run) * NSUB * 32 + ch;
    float acc = 0.f;
    for (int s = 0; s < NSUB; s += 8) {
        float v[8];
        #pragma unroll
        for (int k = 0; k < 8; ++k) v[k] = p[(size_t)(s + k) * 32];
        #pragma unroll
        for (int k = 0; k < 8; ++k) { acc += v[k]; v[k] = acc; }
        #pragma unroll
        for (int k = 0; k < 8; ++k) p[(size_t)(s + k) * 32] = v[k];
    }
}
__global__ __launch_bounds__(64)
void k2_kernel(const void* __restrict__ mk, const void* __restrict__ dk,
               float* __restrict__ partials, float* __restrict__ wtab) {
    if (isbf(dk)) k2_body<true >(mk, partials, wtab);
    else          k2_body<false>(mk, partials, wtab);
}

// ---------------- K3 ----------------
// grid 512 = b(8) x chunk(128) x 128thr/2; thread owns 4 channels (float4), 32 t.
// j: q=j&7 (quad in MA half), run=(j>>3)&15, chunk=(j>>7)&127, b=j>>14.
template<bool BF>
__device__ void k3_body(const void* __restrict__ u, void* __restrict__ out,
                        const float* __restrict__ sp0, const float* __restrict__ wtab) {
    const unsigned j = blockIdx.x * 256 + threadIdx.x;
    const int q = j & 7, run = (j >> 3) & 15, chunk = (j >> 7) & 127, b = (int)(j >> 14);
    const int ch = run * 64 + 32 + q * 4;
    const int cm = q * 4;
    const size_t base = (size_t)b * L_ * D_ + ch;
    const int r = run * 4 + (q >> 1);
    const int   w  = (int)wtab[r * 4 + 0];
    const float k0 = wtab[r * 4 + 1];
    const float km = wtab[r * 4 + 2];
    // sp[s*32..+3] holds scanned prefix P[32(s+1)-1] for this thread's 4 channels
    const float* sp = sp0 + (size_t)(b * NRUN + run) * NSUB * 32 + cm;
    const int t0 = chunk * SUB;
    const float4 z4 = make_float4(0.f, 0.f, 0.f, 0.f);

    float4 acc = (chunk > 0)
        ? *reinterpret_cast<const float4*>(sp + (size_t)(chunk - 1) * 32) : z4;
    const int A = t0 - w;
    if (A > 0) {                                  // min-side fix-up, <=16 loads
        const int m = A >> 5, rem = A & 31;
        if (rem <= 16) {
            if (m > 0) {
                const float4 pv = *reinterpret_cast<const float4*>(sp + (size_t)(m - 1) * 32);
                acc.x -= pv.x; acc.y -= pv.y; acc.z -= pv.z; acc.w -= pv.w;
            }
            for (int s = m * 32; s < A; ++s) {
                const float4 xv = ld4<BF>(u, base + (size_t)s * D_);
                acc.x -= xv.x; acc.y -= xv.y; acc.z -= xv.z; acc.w -= xv.w;
            }
        } else {
            const float4 pv = *reinterpret_cast<const float4*>(sp + (size_t)m * 32);
            acc.x -= pv.x; acc.y -= pv.y; acc.z -= pv.z; acc.w -= pv.w;
            for (int s = A; s < (m + 1) * 32; ++s) {
                const float4 xv = ld4<BF>(u, base + (size_t)s * D_);
                acc.x += xv.x; acc.y += xv.y; acc.z += xv.z; acc.w += xv.w;
            }
        }
    }
    float4 xt[2][4], xl[2][4];
    auto loadb = [&](int buf, int tb) {
        #pragma unroll
        for (int k = 0; k < 4; ++k) {
            const int t = tb + k;
            xt[buf][k] = ld4<BF>(u, base + (size_t)t * D_);
            const int tl = t - w;
            xl[buf][k] = (tl >= 0) ? ld4<BF>(u, base + (size_t)tl * D_) : z4;
        }
    };
    loadb(0, t0);
    #pragma unroll
    for (int bb = 0; bb < SUB; bb += 4) {
        const int cur = (bb >> 2) & 1, nxt = cur ^ 1;
        if (bb + 4 < SUB) loadb(nxt, t0 + bb + 4);
        #pragma unroll
        for (int k = 0; k < 4; ++k) {
            const float4 xv = xt[cur][k];
            acc.x += xv.x - xl[cur][k].x;
            acc.y += xv.y - xl[cur][k].y;
            acc.z += xv.z - xl[cur][k].z;
            acc.w += xv.w - xl[cur][k].w;
            float4 y;
            y.x = k0 * xv.x + km * (acc.x - xv.x);
            y.y = k0 * xv.y + km * (acc.y - xv.y);
            y.z = k0 * xv.z + km * (acc.z - xv.z);
            y.w = k0 * xv.w + km * (acc.w - xv.w);
            st4<BF>(out, base + (size_t)(t0 + bb + k) * D_, y);
        }
    }
}
__global__ __launch_bounds__(256)
void k3_kernel(const void* __restrict__ u, const void* __restrict__ dk,
               void* __restrict__ out, const float* __restrict__ sp0,
               const float* __restrict__ wtab) {
    if (isbf(dk)) k3_body<true >(u, out, sp0, wtab);
    else          k3_body<false>(u, out, sp0, wtab);
}
}  // namespace

extern "C" void kernel_launch(void* const* d_in, const int* in_sizes, int n_in,
                              void* d_out, int out_size, void* d_ws, size_t ws_size,
                              hipStream_t stream) {
    const void* u  = d_in[0];
    const void* dk = d_in[1];
    const void* mk = d_in[2];
    float* partials = (float*)d_ws;
    float* wtab     = (float*)d_ws + NPART;    // 2 MB + 1 KB <= ws_size
    ka_kernel<<<KA_BLOCKS, 256, 0, stream>>>(u, dk, d_out, partials);
    k2_kernel<<<64, 64, 0, stream>>>(mk, dk, partials, wtab);
    k3_kernel<<<K3_BLOCKS, 256, 0, stream>>>(u, dk, d_out, partials, wtab);
}